// Round 3
// baseline (323.887 us; speedup 1.0000x reference)
//
#include <hip/hip_runtime.h>

#define N_NODES 100000
#define N_EDGES 1000000
#define D_FEAT  64

// Binning: 128 consecutive dst nodes per bin.
#define BIN_SHIFT 7
#define BIN_NODES 128
#define NBINS ((N_NODES + BIN_NODES - 1) >> BIN_SHIFT)   // 782
#define BIN_CAP 2560   // mean edges/bin = 1280, sigma ~36 -> 35 sigma headroom

// ---------------------------------------------------------------------------
// Workspace layout (ints):
//   bcnt   [NBINS]    edges per bin
//   bbase  [NBINS]    exclusive scan of bcnt
//   bcur   [NBINS]    scatter cursor (init = bbase)
//   bucket [N_EDGES]  packed (local_dst << 17) | src, grouped by bin
// ---------------------------------------------------------------------------
#define WS_BCNT   0
#define WS_BBASE  (NBINS)
#define WS_BCUR   (2 * NBINS)
#define WS_BUCKET (3 * NBINS)
#define WS_NEEDED ((size_t)(3 * NBINS + N_EDGES) * sizeof(int))

// K1: zero bin counters
__global__ void bin_zero_kernel(int* __restrict__ ws) {
    int i = blockIdx.x * blockDim.x + threadIdx.x;
    if (i < NBINS) ws[WS_BCNT + i] = 0;
}

// K2: per-bin histogram with LDS privatization
__global__ __launch_bounds__(256) void bin_count_kernel(const int* __restrict__ dst,
                                                        int* __restrict__ ws) {
    __shared__ int h[NBINS];
    for (int i = threadIdx.x; i < NBINS; i += 256) h[i] = 0;
    __syncthreads();
    int stride = gridDim.x * blockDim.x;
    for (int e = blockIdx.x * blockDim.x + threadIdx.x; e < N_EDGES; e += stride)
        atomicAdd(&h[dst[e] >> BIN_SHIFT], 1);
    __syncthreads();
    for (int i = threadIdx.x; i < NBINS; i += 256) {
        int v = h[i];
        if (v) atomicAdd(&ws[WS_BCNT + i], v);
    }
}

// K3: exclusive scan of 782 bin counts (single 64-lane wave) + cursor init
__global__ void bin_scan_kernel(int* __restrict__ ws) {
    int lane = threadIdx.x;  // blockDim.x == 64
    int carry = 0;
    for (int c = 0; c < NBINS; c += 64) {
        int idx = c + lane;
        int v = (idx < NBINS) ? ws[WS_BCNT + idx] : 0;
        int incl = v;
        #pragma unroll
        for (int o = 1; o < 64; o <<= 1) {
            int t = __shfl_up(incl, o);
            if (lane >= o) incl += t;
        }
        int excl = carry + incl - v;
        if (idx < NBINS) {
            ws[WS_BBASE + idx] = excl;
            ws[WS_BCUR + idx]  = excl;
        }
        carry += __shfl(incl, 63);
    }
}

// K4: scatter packed (local_dst, src) into bin regions. Hot bin cursors mean
// concurrent writers land in adjacent slots -> line-clustered writes.
__global__ __launch_bounds__(256) void bin_scatter_kernel(const int* __restrict__ src,
                                                          const int* __restrict__ dst,
                                                          int* __restrict__ ws) {
    int stride = gridDim.x * blockDim.x;
    for (int e = blockIdx.x * blockDim.x + threadIdx.x; e < N_EDGES; e += stride) {
        int d = dst[e];
        int s = src[e];
        int bin   = d >> BIN_SHIFT;
        int local = d & (BIN_NODES - 1);
        int slot = atomicAdd(&ws[WS_BCUR + bin], 1);
        ws[WS_BUCKET + slot] = (local << 17) | s;
    }
}

// K5: per-bin fused counting-sort (in LDS) + gather + mean + store.
__global__ __launch_bounds__(256) void fused_gather_kernel(const float* __restrict__ emb,
                                                           const int* __restrict__ ws,
                                                           float* __restrict__ out) {
    __shared__ int s_edges[BIN_CAP];
    __shared__ int s_sorted[BIN_CAP];
    __shared__ int s_hist[BIN_NODES];
    __shared__ int s_off[BIN_NODES];
    __shared__ int s_cur[BIN_NODES];

    int b   = blockIdx.x;
    int tid = threadIdx.x;
    int cnt  = ws[WS_BCNT + b];
    if (cnt > BIN_CAP) cnt = BIN_CAP;   // statistically impossible; defensive
    int base = ws[WS_BBASE + b];

    for (int i = tid; i < BIN_NODES; i += 256) s_hist[i] = 0;
    __syncthreads();

    // load bin edges + LDS histogram by local dst
    for (int i = tid; i < cnt; i += 256) {
        int p = ws[WS_BUCKET + base + i];
        s_edges[i] = p;
        atomicAdd(&s_hist[p >> 17], 1);
    }
    __syncthreads();

    // scan 128 hist entries with wave 0
    if (tid < 64) {
        int carry = 0;
        #pragma unroll
        for (int c = 0; c < BIN_NODES; c += 64) {
            int v = s_hist[c + tid];
            int incl = v;
            #pragma unroll
            for (int o = 1; o < 64; o <<= 1) {
                int t = __shfl_up(incl, o);
                if (tid >= o) incl += t;
            }
            int excl = carry + incl - v;
            s_off[c + tid] = excl;
            s_cur[c + tid] = excl;
            carry += __shfl(incl, 63);
        }
    }
    __syncthreads();

    // counting-sort scatter within LDS
    for (int i = tid; i < cnt; i += 256) {
        int p = s_edges[i];
        int slot = atomicAdd(&s_cur[p >> 17], 1);
        s_sorted[slot] = p & 0x1FFFF;
    }
    __syncthreads();

    // gather: 4 waves x 32 nodes; lane == feature
    int wave = tid >> 6, lane = tid & 63;
    for (int ln = wave * 32; ln < wave * 32 + 32; ++ln) {
        int node = (b << BIN_SHIFT) + ln;
        if (node >= N_NODES) break;
        int deg = s_hist[ln];
        int off = s_off[ln];
        float acc = 0.0f;
        int i = 0;
        for (; i + 4 <= deg; i += 4) {
            int s0 = s_sorted[off + i + 0];
            int s1 = s_sorted[off + i + 1];
            int s2 = s_sorted[off + i + 2];
            int s3 = s_sorted[off + i + 3];
            float v0 = emb[(size_t)s0 * D_FEAT + lane];
            float v1 = emb[(size_t)s1 * D_FEAT + lane];
            float v2 = emb[(size_t)s2 * D_FEAT + lane];
            float v3 = emb[(size_t)s3 * D_FEAT + lane];
            acc += v0; acc += v1; acc += v2; acc += v3;
        }
        for (; i < deg; ++i) {
            int s = s_sorted[off + i];
            acc += emb[(size_t)s * D_FEAT + lane];
        }
        out[(size_t)node * D_FEAT + lane] = acc / (float)max(deg, 1);
    }
}

// ======================= Fallback (R1 atomic path) =========================

__global__ void gcn_zero_kernel(float* __restrict__ out, float* __restrict__ counts) {
    int stride = gridDim.x * blockDim.x;
    int i = blockIdx.x * blockDim.x + threadIdx.x;
    const int total = N_NODES * D_FEAT;
    for (int idx = i; idx < total; idx += stride) out[idx] = 0.0f;
    for (int idx = i; idx < N_NODES; idx += stride) counts[idx] = 0.0f;
}

__global__ void gcn_scatter_kernel(const float* __restrict__ emb,
                                   const int* __restrict__ src,
                                   const int* __restrict__ dst,
                                   float* __restrict__ out,
                                   float* __restrict__ counts) {
    int gid  = blockIdx.x * blockDim.x + threadIdx.x;
    int edge = gid >> 6;
    int lane = gid & 63;
    if (edge >= N_EDGES) return;
    int s = src[edge];
    int d = dst[edge];
    float v = emb[(size_t)s * D_FEAT + lane];
    atomicAdd(&out[(size_t)d * D_FEAT + lane], v);
    if (lane == 0) atomicAdd(&counts[d], 1.0f);
}

__global__ void gcn_norm_kernel(float* __restrict__ out,
                                const float* __restrict__ counts) {
    int i = blockIdx.x * blockDim.x + threadIdx.x;
    if (i >= N_NODES * D_FEAT) return;
    int n = i >> 6;
    float c = counts[n];
    out[i] *= (1.0f / fmaxf(c, 1.0f));
}

// ===========================================================================

extern "C" void kernel_launch(void* const* d_in, const int* in_sizes, int n_in,
                              void* d_out, int out_size, void* d_ws, size_t ws_size,
                              hipStream_t stream) {
    const float* emb = (const float*)d_in[0];
    const int*   src = (const int*)d_in[1];
    const int*   dst = (const int*)d_in[2];
    float* out = (float*)d_out;

    if (ws_size >= WS_NEEDED) {
        int* ws = (int*)d_ws;
        bin_zero_kernel<<<(NBINS + 255) / 256, 256, 0, stream>>>(ws);
        bin_count_kernel<<<128, 256, 0, stream>>>(dst, ws);
        bin_scan_kernel<<<1, 64, 0, stream>>>(ws);
        bin_scatter_kernel<<<2048, 256, 0, stream>>>(src, dst, ws);
        fused_gather_kernel<<<NBINS, 256, 0, stream>>>(emb, ws, out);
    } else {
        float* counts = (float*)d_ws;
        gcn_zero_kernel<<<2048, 256, 0, stream>>>(out, counts);
        const int scatter_blocks = (N_EDGES * 64) / 256;
        gcn_scatter_kernel<<<scatter_blocks, 256, 0, stream>>>(emb, src, dst, out, counts);
        const int norm_blocks = (N_NODES * D_FEAT + 255) / 256;
        gcn_norm_kernel<<<norm_blocks, 256, 0, stream>>>(out, counts);
    }
}

// Round 4
// 96.873 us; speedup vs baseline: 3.3434x; 3.3434x over previous
//
#include <hip/hip_runtime.h>

#define N_NODES 100000
#define N_EDGES 1000000
#define D_FEAT  64

// Binning: 128 consecutive dst nodes per bin.
#define BIN_SHIFT 7
#define BIN_NODES 128
#define NBINS ((N_NODES + BIN_NODES - 1) >> BIN_SHIFT)   // 782
#define BIN_CAP 2560   // mean edges/bin = 1280, sigma ~36

// Deterministic partition: NB_PART contiguous edge chunks, radix-style.
#define NB_PART 128
#define CHUNK ((N_EDGES + NB_PART - 1) / NB_PART)        // 7813

// ---------------------------------------------------------------------------
// Workspace layout (ints):
//   H      [NBINS][NB_PART]  per-(bin,block) histogram -> exclusive offsets
//   T      [NBINS]           per-bin totals
//   BASE   [NBINS]           exclusive scan of T
//   bucket [N_EDGES]         packed (local_dst << 17) | src, grouped by bin
// ---------------------------------------------------------------------------
#define WS_H      0
#define WS_T      (NBINS * NB_PART)
#define WS_BASE   (WS_T + NBINS)
#define WS_BUCKET (WS_BASE + NBINS)
#define WS_NEEDED ((size_t)(WS_BUCKET + N_EDGES) * sizeof(int))

// KA: per-block histogram of its contiguous edge chunk (LDS privatized)
__global__ __launch_bounds__(256) void part_hist_kernel(const int* __restrict__ dst,
                                                        int* __restrict__ ws) {
    __shared__ int h[NBINS];
    for (int j = threadIdx.x; j < NBINS; j += 256) h[j] = 0;
    __syncthreads();
    int blk = blockIdx.x;
    int e0 = blk * CHUNK, e1 = min(N_EDGES, e0 + CHUNK);
    for (int e = e0 + threadIdx.x; e < e1; e += 256)
        atomicAdd(&h[dst[e] >> BIN_SHIFT], 1);
    __syncthreads();
    for (int j = threadIdx.x; j < NBINS; j += 256)
        ws[WS_H + j * NB_PART + blk] = h[j];
}

// KB: per-bin exclusive scan across the 128 blocks (one wave per bin),
// leaves exclusive offsets in H and bin totals in T.
__global__ __launch_bounds__(256) void part_colscan_kernel(int* __restrict__ ws) {
    int wave = threadIdx.x >> 6;
    int lane = threadIdx.x & 63;
    int j = blockIdx.x * 4 + wave;
    if (j >= NBINS) return;
    int* Hrow = ws + WS_H + j * NB_PART;

    int v0 = Hrow[lane];
    int incl0 = v0;
    #pragma unroll
    for (int o = 1; o < 64; o <<= 1) {
        int t = __shfl_up(incl0, o);
        if (lane >= o) incl0 += t;
    }
    int excl0 = incl0 - v0;
    int tot0 = __shfl(incl0, 63);

    int v1 = Hrow[64 + lane];
    int incl1 = v1;
    #pragma unroll
    for (int o = 1; o < 64; o <<= 1) {
        int t = __shfl_up(incl1, o);
        if (lane >= o) incl1 += t;
    }
    int excl1 = tot0 + incl1 - v1;

    Hrow[lane]      = excl0;
    Hrow[64 + lane] = excl1;
    if (lane == 63) ws[WS_T + j] = tot0 + incl1;
}

// KC: single-wave exclusive scan of the 782 bin totals -> BASE
__global__ void base_scan_kernel(int* __restrict__ ws) {
    int lane = threadIdx.x;  // blockDim.x == 64
    int carry = 0;
    for (int c = 0; c < NBINS; c += 64) {
        int idx = c + lane;
        int v = (idx < NBINS) ? ws[WS_T + idx] : 0;
        int incl = v;
        #pragma unroll
        for (int o = 1; o < 64; o <<= 1) {
            int t = __shfl_up(incl, o);
            if (lane >= o) incl += t;
        }
        if (idx < NBINS) ws[WS_BASE + idx] = carry + incl - v;
        carry += __shfl(incl, 63);
    }
}

// KE: re-read chunk, rank via LDS cursors (no global atomics), write packed
// edges into per-(block,bin) contiguous runs.
__global__ __launch_bounds__(256) void part_scatter_kernel(const int* __restrict__ src,
                                                           const int* __restrict__ dst,
                                                           int* __restrict__ ws) {
    __shared__ int cur[NBINS];
    int blk = blockIdx.x;
    for (int j = threadIdx.x; j < NBINS; j += 256)
        cur[j] = ws[WS_BASE + j] + ws[WS_H + j * NB_PART + blk];
    __syncthreads();
    int e0 = blk * CHUNK, e1 = min(N_EDGES, e0 + CHUNK);
    for (int e = e0 + threadIdx.x; e < e1; e += 256) {
        int d = dst[e], s = src[e];
        int j = d >> BIN_SHIFT;
        int slot = atomicAdd(&cur[j], 1);          // LDS atomic
        ws[WS_BUCKET + slot] = ((d & (BIN_NODES - 1)) << 17) | s;
    }
}

// K5: per-bin fused counting-sort (in LDS) + gather + mean + store.
__global__ __launch_bounds__(256) void fused_gather_kernel(const float* __restrict__ emb,
                                                           const int* __restrict__ ws,
                                                           float* __restrict__ out) {
    __shared__ int s_edges[BIN_CAP];
    __shared__ int s_sorted[BIN_CAP];
    __shared__ int s_hist[BIN_NODES];
    __shared__ int s_off[BIN_NODES];
    __shared__ int s_cur[BIN_NODES];

    int b   = blockIdx.x;
    int tid = threadIdx.x;
    int cnt  = ws[WS_T + b];
    if (cnt > BIN_CAP) cnt = BIN_CAP;   // statistically impossible; defensive
    int base = ws[WS_BASE + b];

    for (int i = tid; i < BIN_NODES; i += 256) s_hist[i] = 0;
    __syncthreads();

    for (int i = tid; i < cnt; i += 256) {
        int p = ws[WS_BUCKET + base + i];
        s_edges[i] = p;
        atomicAdd(&s_hist[p >> 17], 1);
    }
    __syncthreads();

    if (tid < 64) {
        int carry = 0;
        #pragma unroll
        for (int c = 0; c < BIN_NODES; c += 64) {
            int v = s_hist[c + tid];
            int incl = v;
            #pragma unroll
            for (int o = 1; o < 64; o <<= 1) {
                int t = __shfl_up(incl, o);
                if (tid >= o) incl += t;
            }
            int excl = carry + incl - v;
            s_off[c + tid] = excl;
            s_cur[c + tid] = excl;
            carry += __shfl(incl, 63);
        }
    }
    __syncthreads();

    for (int i = tid; i < cnt; i += 256) {
        int p = s_edges[i];
        int slot = atomicAdd(&s_cur[p >> 17], 1);
        s_sorted[slot] = p & 0x1FFFF;
    }
    __syncthreads();

    int wave = tid >> 6, lane = tid & 63;
    for (int ln = wave * 32; ln < wave * 32 + 32; ++ln) {
        int node = (b << BIN_SHIFT) + ln;
        if (node >= N_NODES) break;
        int deg = s_hist[ln];
        int off = s_off[ln];
        float acc = 0.0f;
        int i = 0;
        for (; i + 4 <= deg; i += 4) {
            int s0 = s_sorted[off + i + 0];
            int s1 = s_sorted[off + i + 1];
            int s2 = s_sorted[off + i + 2];
            int s3 = s_sorted[off + i + 3];
            float v0 = emb[(size_t)s0 * D_FEAT + lane];
            float v1 = emb[(size_t)s1 * D_FEAT + lane];
            float v2 = emb[(size_t)s2 * D_FEAT + lane];
            float v3 = emb[(size_t)s3 * D_FEAT + lane];
            acc += v0; acc += v1; acc += v2; acc += v3;
        }
        for (; i < deg; ++i) {
            int s = s_sorted[off + i];
            acc += emb[(size_t)s * D_FEAT + lane];
        }
        out[(size_t)node * D_FEAT + lane] = acc / (float)max(deg, 1);
    }
}

// ======================= Fallback (R1 atomic path) =========================

__global__ void gcn_zero_kernel(float* __restrict__ out, float* __restrict__ counts) {
    int stride = gridDim.x * blockDim.x;
    int i = blockIdx.x * blockDim.x + threadIdx.x;
    const int total = N_NODES * D_FEAT;
    for (int idx = i; idx < total; idx += stride) out[idx] = 0.0f;
    for (int idx = i; idx < N_NODES; idx += stride) counts[idx] = 0.0f;
}

__global__ void gcn_scatter_kernel(const float* __restrict__ emb,
                                   const int* __restrict__ src,
                                   const int* __restrict__ dst,
                                   float* __restrict__ out,
                                   float* __restrict__ counts) {
    int gid  = blockIdx.x * blockDim.x + threadIdx.x;
    int edge = gid >> 6;
    int lane = gid & 63;
    if (edge >= N_EDGES) return;
    int s = src[edge];
    int d = dst[edge];
    float v = emb[(size_t)s * D_FEAT + lane];
    atomicAdd(&out[(size_t)d * D_FEAT + lane], v);
    if (lane == 0) atomicAdd(&counts[d], 1.0f);
}

__global__ void gcn_norm_kernel(float* __restrict__ out,
                                const float* __restrict__ counts) {
    int i = blockIdx.x * blockDim.x + threadIdx.x;
    if (i >= N_NODES * D_FEAT) return;
    int n = i >> 6;
    float c = counts[n];
    out[i] *= (1.0f / fmaxf(c, 1.0f));
}

// ===========================================================================

extern "C" void kernel_launch(void* const* d_in, const int* in_sizes, int n_in,
                              void* d_out, int out_size, void* d_ws, size_t ws_size,
                              hipStream_t stream) {
    const float* emb = (const float*)d_in[0];
    const int*   src = (const int*)d_in[1];
    const int*   dst = (const int*)d_in[2];
    float* out = (float*)d_out;

    if (ws_size >= WS_NEEDED) {
        int* ws = (int*)d_ws;
        part_hist_kernel<<<NB_PART, 256, 0, stream>>>(dst, ws);
        part_colscan_kernel<<<(NBINS + 3) / 4, 256, 0, stream>>>(ws);
        base_scan_kernel<<<1, 64, 0, stream>>>(ws);
        part_scatter_kernel<<<NB_PART, 256, 0, stream>>>(src, dst, ws);
        fused_gather_kernel<<<NBINS, 256, 0, stream>>>(emb, ws, out);
    } else {
        float* counts = (float*)d_ws;
        gcn_zero_kernel<<<2048, 256, 0, stream>>>(out, counts);
        const int scatter_blocks = (N_EDGES * 64) / 256;
        gcn_scatter_kernel<<<scatter_blocks, 256, 0, stream>>>(emb, src, dst, out, counts);
        const int norm_blocks = (N_NODES * D_FEAT + 255) / 256;
        gcn_norm_kernel<<<norm_blocks, 256, 0, stream>>>(out, counts);
    }
}

// Round 5
// 87.333 us; speedup vs baseline: 3.7086x; 1.1092x over previous
//
#include <hip/hip_runtime.h>

#define N_NODES 100000
#define N_EDGES 1000000
#define D_FEAT  64

// Binning: 64 consecutive dst nodes per bin (more blocks -> more waves in flight)
#define BIN_SHIFT 6
#define BIN_NODES 64
#define NBINS ((N_NODES + BIN_NODES - 1) >> BIN_SHIFT)   // 1563
#define BIN_CAP 1536   // mean edges/bin = 640, sigma ~25 -> ~35 sigma headroom

// Deterministic partition: NB_PART contiguous edge chunks, radix-style.
#define NB_PART 128
#define CHUNK ((N_EDGES + NB_PART - 1) / NB_PART)        // 7813

// ---------------------------------------------------------------------------
// Workspace layout (ints):
//   H      [NBINS][NB_PART]  per-(bin,block) histogram -> exclusive offsets
//   T      [NBINS]           per-bin totals
//   BASE   [NBINS]           exclusive scan of T
//   bucket [N_EDGES]         packed (local_dst << 17) | src, grouped by bin
// ---------------------------------------------------------------------------
#define WS_H      0
#define WS_T      (NBINS * NB_PART)
#define WS_BASE   (WS_T + NBINS)
#define WS_BUCKET (WS_BASE + NBINS)
#define WS_NEEDED ((size_t)(WS_BUCKET + N_EDGES) * sizeof(int))

// KA: per-block histogram of its contiguous edge chunk (LDS privatized)
__global__ __launch_bounds__(256) void part_hist_kernel(const int* __restrict__ dst,
                                                        int* __restrict__ ws) {
    __shared__ int h[NBINS];
    for (int j = threadIdx.x; j < NBINS; j += 256) h[j] = 0;
    __syncthreads();
    int blk = blockIdx.x;
    int e0 = blk * CHUNK, e1 = min(N_EDGES, e0 + CHUNK);
    for (int e = e0 + threadIdx.x; e < e1; e += 256)
        atomicAdd(&h[dst[e] >> BIN_SHIFT], 1);
    __syncthreads();
    for (int j = threadIdx.x; j < NBINS; j += 256)
        ws[WS_H + j * NB_PART + blk] = h[j];
}

// KB: per-bin exclusive scan across the 128 blocks (one wave per bin),
// leaves exclusive offsets in H and bin totals in T.
__global__ __launch_bounds__(256) void part_colscan_kernel(int* __restrict__ ws) {
    int wave = threadIdx.x >> 6;
    int lane = threadIdx.x & 63;
    int j = blockIdx.x * 4 + wave;
    if (j >= NBINS) return;
    int* Hrow = ws + WS_H + j * NB_PART;

    int v0 = Hrow[lane];
    int incl0 = v0;
    #pragma unroll
    for (int o = 1; o < 64; o <<= 1) {
        int t = __shfl_up(incl0, o);
        if (lane >= o) incl0 += t;
    }
    int excl0 = incl0 - v0;
    int tot0 = __shfl(incl0, 63);

    int v1 = Hrow[64 + lane];
    int incl1 = v1;
    #pragma unroll
    for (int o = 1; o < 64; o <<= 1) {
        int t = __shfl_up(incl1, o);
        if (lane >= o) incl1 += t;
    }
    int excl1 = tot0 + incl1 - v1;

    Hrow[lane]      = excl0;
    Hrow[64 + lane] = excl1;
    if (lane == 63) ws[WS_T + j] = tot0 + incl1;
}

// KC: single-wave exclusive scan of the bin totals -> BASE
__global__ void base_scan_kernel(int* __restrict__ ws) {
    int lane = threadIdx.x;  // blockDim.x == 64
    int carry = 0;
    for (int c = 0; c < NBINS; c += 64) {
        int idx = c + lane;
        int v = (idx < NBINS) ? ws[WS_T + idx] : 0;
        int incl = v;
        #pragma unroll
        for (int o = 1; o < 64; o <<= 1) {
            int t = __shfl_up(incl, o);
            if (lane >= o) incl += t;
        }
        if (idx < NBINS) ws[WS_BASE + idx] = carry + incl - v;
        carry += __shfl(incl, 63);
    }
}

// KE: re-read chunk, rank via LDS cursors (no global atomics), write packed
// edges into per-(block,bin) contiguous runs.
__global__ __launch_bounds__(256) void part_scatter_kernel(const int* __restrict__ src,
                                                           const int* __restrict__ dst,
                                                           int* __restrict__ ws) {
    __shared__ int cur[NBINS];
    int blk = blockIdx.x;
    for (int j = threadIdx.x; j < NBINS; j += 256)
        cur[j] = ws[WS_BASE + j] + ws[WS_H + j * NB_PART + blk];
    __syncthreads();
    int e0 = blk * CHUNK, e1 = min(N_EDGES, e0 + CHUNK);
    for (int e = e0 + threadIdx.x; e < e1; e += 256) {
        int d = dst[e], s = src[e];
        int j = d >> BIN_SHIFT;
        int slot = atomicAdd(&cur[j], 1);          // LDS atomic
        ws[WS_BUCKET + slot] = ((d & (BIN_NODES - 1)) << 17) | s;
    }
}

// K5: per-bin fused counting-sort (in LDS) + float4 gather + mean + store.
// Gather: 16 lanes per row, 4 edges per wave-instruction (1KB in flight),
// unrolled x2; 2-step shfl_xor reduce across edge subgroups.
__global__ __launch_bounds__(256) void fused_gather_kernel(const float* __restrict__ emb,
                                                           const int* __restrict__ ws,
                                                           float* __restrict__ out) {
    __shared__ int s_edges[BIN_CAP];
    __shared__ int s_sorted[BIN_CAP];
    __shared__ int s_hist[BIN_NODES];
    __shared__ int s_off[BIN_NODES];
    __shared__ int s_cur[BIN_NODES];

    int b   = blockIdx.x;
    int tid = threadIdx.x;
    int cnt  = ws[WS_T + b];
    if (cnt > BIN_CAP) cnt = BIN_CAP;   // statistically impossible; defensive
    int base = ws[WS_BASE + b];

    if (tid < BIN_NODES) s_hist[tid] = 0;
    __syncthreads();

    for (int i = tid; i < cnt; i += 256) {
        int p = ws[WS_BUCKET + base + i];
        s_edges[i] = p;
        atomicAdd(&s_hist[p >> 17], 1);
    }
    __syncthreads();

    // scan 64 hist entries with wave 0
    if (tid < 64) {
        int v = s_hist[tid];
        int incl = v;
        #pragma unroll
        for (int o = 1; o < 64; o <<= 1) {
            int t = __shfl_up(incl, o);
            if (tid >= o) incl += t;
        }
        int excl = incl - v;
        s_off[tid] = excl;
        s_cur[tid] = excl;
    }
    __syncthreads();

    // counting-sort scatter within LDS
    for (int i = tid; i < cnt; i += 256) {
        int p = s_edges[i];
        int slot = atomicAdd(&s_cur[p >> 17], 1);
        s_sorted[slot] = p & 0x1FFFF;
    }
    __syncthreads();

    // gather: 4 waves x 16 nodes; within a wave: sub = edge slot (0..3),
    // fq = feature quarter (float4)
    int wave = tid >> 6, lane = tid & 63;
    int sub  = lane >> 4;        // which edge of the group of 4
    int fq   = lane & 15;        // which float4 of the row

    for (int ln = wave * 16; ln < wave * 16 + 16; ++ln) {
        int node = (b << BIN_SHIFT) + ln;
        if (node >= N_NODES) break;
        int deg = s_hist[ln];
        int off = s_off[ln];

        float4 acc = make_float4(0.f, 0.f, 0.f, 0.f);
        int i = sub;
        for (; i + 4 < deg; i += 8) {
            int s0 = s_sorted[off + i];
            int s1 = s_sorted[off + i + 4];
            const float4* r0 = (const float4*)(emb + (size_t)s0 * D_FEAT);
            const float4* r1 = (const float4*)(emb + (size_t)s1 * D_FEAT);
            float4 v0 = r0[fq];
            float4 v1 = r1[fq];
            acc.x += v0.x + v1.x;
            acc.y += v0.y + v1.y;
            acc.z += v0.z + v1.z;
            acc.w += v0.w + v1.w;
        }
        if (i < deg) {
            int s0 = s_sorted[off + i];
            const float4* r0 = (const float4*)(emb + (size_t)s0 * D_FEAT);
            float4 v0 = r0[fq];
            acc.x += v0.x; acc.y += v0.y; acc.z += v0.z; acc.w += v0.w;
        }

        // reduce across the 4 edge subgroups (lanes l, l^16, l^32, l^48)
        #pragma unroll
        for (int m = 16; m < 64; m <<= 1) {
            acc.x += __shfl_xor(acc.x, m);
            acc.y += __shfl_xor(acc.y, m);
            acc.z += __shfl_xor(acc.z, m);
            acc.w += __shfl_xor(acc.w, m);
        }

        if (sub == 0) {
            float inv = 1.0f / (float)max(deg, 1);
            acc.x *= inv; acc.y *= inv; acc.z *= inv; acc.w *= inv;
            *(float4*)(out + (size_t)node * D_FEAT + fq * 4) = acc;
        }
    }
}

// ======================= Fallback (R1 atomic path) =========================

__global__ void gcn_zero_kernel(float* __restrict__ out, float* __restrict__ counts) {
    int stride = gridDim.x * blockDim.x;
    int i = blockIdx.x * blockDim.x + threadIdx.x;
    const int total = N_NODES * D_FEAT;
    for (int idx = i; idx < total; idx += stride) out[idx] = 0.0f;
    for (int idx = i; idx < N_NODES; idx += stride) counts[idx] = 0.0f;
}

__global__ void gcn_scatter_kernel(const float* __restrict__ emb,
                                   const int* __restrict__ src,
                                   const int* __restrict__ dst,
                                   float* __restrict__ out,
                                   float* __restrict__ counts) {
    int gid  = blockIdx.x * blockDim.x + threadIdx.x;
    int edge = gid >> 6;
    int lane = gid & 63;
    if (edge >= N_EDGES) return;
    int s = src[edge];
    int d = dst[edge];
    float v = emb[(size_t)s * D_FEAT + lane];
    atomicAdd(&out[(size_t)d * D_FEAT + lane], v);
    if (lane == 0) atomicAdd(&counts[d], 1.0f);
}

__global__ void gcn_norm_kernel(float* __restrict__ out,
                                const float* __restrict__ counts) {
    int i = blockIdx.x * blockDim.x + threadIdx.x;
    if (i >= N_NODES * D_FEAT) return;
    int n = i >> 6;
    float c = counts[n];
    out[i] *= (1.0f / fmaxf(c, 1.0f));
}

// ===========================================================================

extern "C" void kernel_launch(void* const* d_in, const int* in_sizes, int n_in,
                              void* d_out, int out_size, void* d_ws, size_t ws_size,
                              hipStream_t stream) {
    const float* emb = (const float*)d_in[0];
    const int*   src = (const int*)d_in[1];
    const int*   dst = (const int*)d_in[2];
    float* out = (float*)d_out;

    if (ws_size >= WS_NEEDED) {
        int* ws = (int*)d_ws;
        part_hist_kernel<<<NB_PART, 256, 0, stream>>>(dst, ws);
        part_colscan_kernel<<<(NBINS + 3) / 4, 256, 0, stream>>>(ws);
        base_scan_kernel<<<1, 64, 0, stream>>>(ws);
        part_scatter_kernel<<<NB_PART, 256, 0, stream>>>(src, dst, ws);
        fused_gather_kernel<<<NBINS, 256, 0, stream>>>(emb, ws, out);
    } else {
        float* counts = (float*)d_ws;
        gcn_zero_kernel<<<2048, 256, 0, stream>>>(out, counts);
        const int scatter_blocks = (N_EDGES * 64) / 256;
        gcn_scatter_kernel<<<scatter_blocks, 256, 0, stream>>>(emb, src, dst, out, counts);
        const int norm_blocks = (N_NODES * D_FEAT + 255) / 256;
        gcn_norm_kernel<<<norm_blocks, 256, 0, stream>>>(out, counts);
    }
}